// Round 1
// baseline (1143.117 us; speedup 1.0000x reference)
//
#include <hip/hip_runtime.h>

#define N_NODES_C 100000
#define N_EDGES_C 1600000
#define N_GRAPHS_C 2000
#define HID 128
#define BN_EPS_C 1e-5f

// ---------------- CSR build ----------------

__global__ __launch_bounds__(256) void k_count(const int* __restrict__ dst, int* __restrict__ counts) {
    int e = blockIdx.x * 256 + threadIdx.x;
    if (e < N_EDGES_C) atomicAdd(&counts[dst[e]], 1);
}

__global__ __launch_bounds__(256) void k_norm(const int* __restrict__ counts,
                                              float* __restrict__ norm, float* __restrict__ selfc) {
    int i = blockIdx.x * 256 + threadIdx.x;
    if (i < N_NODES_C) {
        float d = (float)counts[i] + 1.0f;
        float r = rsqrtf(d);
        norm[i]  = r;
        selfc[i] = r * r;
    }
}

__global__ __launch_bounds__(256) void k_scan1(const int* __restrict__ counts,
                                               int* __restrict__ tmp_incl, int* __restrict__ blockSums) {
    __shared__ int s[256];
    int i = blockIdx.x * 256 + threadIdx.x;
    int v = (i < N_NODES_C) ? counts[i] : 0;
    s[threadIdx.x] = v;
    __syncthreads();
    for (int off = 1; off < 256; off <<= 1) {
        int t = (threadIdx.x >= off) ? s[threadIdx.x - off] : 0;
        __syncthreads();
        s[threadIdx.x] += t;
        __syncthreads();
    }
    if (i < N_NODES_C) tmp_incl[i] = s[threadIdx.x];
    if (threadIdx.x == 255) blockSums[blockIdx.x] = s[255];
}

__global__ __launch_bounds__(512) void k_scan2(const int* __restrict__ blockSums,
                                               int* __restrict__ blockBase, int nblk) {
    __shared__ int s[512];
    int v = ((int)threadIdx.x < nblk) ? blockSums[threadIdx.x] : 0;
    s[threadIdx.x] = v;
    __syncthreads();
    for (int off = 1; off < 512; off <<= 1) {
        int t = (threadIdx.x >= off) ? s[threadIdx.x - off] : 0;
        __syncthreads();
        s[threadIdx.x] += t;
        __syncthreads();
    }
    if ((int)threadIdx.x < nblk) blockBase[threadIdx.x] = s[threadIdx.x] - v;  // exclusive base
}

__global__ __launch_bounds__(256) void k_scan3(const int* __restrict__ tmp_incl,
                                               const int* __restrict__ blockBase, int* __restrict__ offs) {
    int i = blockIdx.x * 256 + threadIdx.x;
    if (i < N_NODES_C) offs[i + 1] = tmp_incl[i] + blockBase[i >> 8];
    if (i == 0) offs[0] = 0;
}

__global__ __launch_bounds__(256) void k_fill(const int* __restrict__ src, const int* __restrict__ dst,
                                              const int* __restrict__ offs, int* __restrict__ cursor,
                                              const float* __restrict__ norm,
                                              int* __restrict__ csr_src, float* __restrict__ csr_coef) {
    int e = blockIdx.x * 256 + threadIdx.x;
    if (e < N_EDGES_C) {
        int d = dst[e], s = src[e];
        int p = offs[d] + atomicAdd(&cursor[d], 1);
        csr_src[p]  = s;
        csr_coef[p] = norm[s] * norm[d];
    }
}

// ---------------- GEMM: C[nrows x 128] = A[nrows x 128] * W[128 x 128] ----------------
// Block: 256 threads -> 128 rows x 128 cols tile. Thread: 4 rows x 16 cols register tile.
// W fully staged in LDS (64 KB). A read from global (8-lane broadcast coalesces per instr).

__global__ __launch_bounds__(256) void k_gemm(const float* __restrict__ A, const float* __restrict__ W,
                                              float* __restrict__ C, int nrows) {
    __shared__ float Ws[HID * HID];
    const int tid = threadIdx.x;
    #pragma unroll
    for (int t = 0; t < 16; t++)
        ((float4*)Ws)[tid + t * 256] = ((const float4*)W)[tid + t * 256];
    __syncthreads();

    const int r0 = blockIdx.x * 128 + (tid >> 3) * 4;
    const int c0 = (tid & 7) * 16;

    float acc[4][16];
    #pragma unroll
    for (int i = 0; i < 4; i++)
        #pragma unroll
        for (int j = 0; j < 16; j++) acc[i][j] = 0.f;

    for (int k0 = 0; k0 < HID; k0 += 4) {
        float a[4][4];
        #pragma unroll
        for (int i = 0; i < 4; i++) {
            int r = r0 + i;
            float4 t = (r < nrows) ? *(const float4*)&A[(long)r * HID + k0] : make_float4(0.f, 0.f, 0.f, 0.f);
            a[i][0] = t.x; a[i][1] = t.y; a[i][2] = t.z; a[i][3] = t.w;
        }
        #pragma unroll
        for (int kk = 0; kk < 4; kk++) {
            float w[16];
            #pragma unroll
            for (int q = 0; q < 4; q++) {
                float4 t = *(const float4*)&Ws[(k0 + kk) * HID + c0 + q * 4];
                w[q * 4 + 0] = t.x; w[q * 4 + 1] = t.y; w[q * 4 + 2] = t.z; w[q * 4 + 3] = t.w;
            }
            #pragma unroll
            for (int i = 0; i < 4; i++)
                #pragma unroll
                for (int j = 0; j < 16; j++)
                    acc[i][j] = fmaf(a[i][kk], w[j], acc[i][j]);
        }
    }
    #pragma unroll
    for (int i = 0; i < 4; i++) {
        int r = r0 + i;
        if (r < nrows) {
            #pragma unroll
            for (int q = 0; q < 4; q++) {
                float4 t;
                t.x = acc[i][q * 4 + 0]; t.y = acc[i][q * 4 + 1];
                t.z = acc[i][q * 4 + 2]; t.w = acc[i][q * 4 + 3];
                *(float4*)&C[(long)r * HID + c0 + q * 4] = t;
            }
        }
    }
}

// ---------------- Aggregation + bias + BN(eval) + ReLU ----------------
// One block (128 threads = channels) per node; gather xw rows of CSR neighbors.

__global__ __launch_bounds__(128) void k_agg(const float* __restrict__ xw, const int* __restrict__ offs,
                                             const int* __restrict__ csr_src, const float* __restrict__ csr_coef,
                                             const float* __restrict__ selfc, const float* __restrict__ bias,
                                             const float* __restrict__ mean, const float* __restrict__ gamma,
                                             const float* __restrict__ var, const float* __restrict__ beta,
                                             float* __restrict__ h) {
    const int i = blockIdx.x;
    const int j = threadIdx.x;
    const int e0 = offs[i], e1 = offs[i + 1];
    float acc = xw[(long)i * HID + j] * selfc[i];
    int e = e0;
    for (; e + 4 <= e1; e += 4) {   // 4-wide software pipeline: 4 gathers in flight
        int   s0 = csr_src[e],  s1 = csr_src[e + 1],  s2 = csr_src[e + 2],  s3 = csr_src[e + 3];
        float c0 = csr_coef[e], c1 = csr_coef[e + 1], c2 = csr_coef[e + 2], c3 = csr_coef[e + 3];
        float x0 = xw[(long)s0 * HID + j], x1 = xw[(long)s1 * HID + j];
        float x2 = xw[(long)s2 * HID + j], x3 = xw[(long)s3 * HID + j];
        acc = fmaf(c0, x0, acc); acc = fmaf(c1, x1, acc);
        acc = fmaf(c2, x2, acc); acc = fmaf(c3, x3, acc);
    }
    for (; e < e1; e++)
        acc = fmaf(csr_coef[e], xw[(long)csr_src[e] * HID + j], acc);

    float scale = gamma[j] * rsqrtf(var[j] + BN_EPS_C);
    float v = (acc + bias[j] - mean[j]) * scale + beta[j];
    h[(long)i * HID + j] = fmaxf(v, 0.f);
}

// ---------------- Pooling (batch is sorted -> run-length local accumulation) ----------------

__global__ __launch_bounds__(128) void k_pool(const float* __restrict__ h, const int* __restrict__ batch,
                                              float* __restrict__ psum, int* __restrict__ pcount) {
    const int j = threadIdx.x;
    const int i0 = blockIdx.x * 128;
    const int iend = min(i0 + 128, N_NODES_C);
    if (i0 >= N_NODES_C) return;
    float acc = 0.f;
    int cur = batch[i0];
    int runStart = i0;
    for (int i = i0; i < iend; i++) {
        int g = batch[i];
        if (g != cur) {
            atomicAdd(&psum[(long)cur * HID + j], acc);
            if (j == 0) atomicAdd(&pcount[cur], i - runStart);
            acc = 0.f; cur = g; runStart = i;
        }
        acc += h[(long)i * HID + j];
    }
    atomicAdd(&psum[(long)cur * HID + j], acc);
    if (j == 0) atomicAdd(&pcount[cur], iend - runStart);
}

__global__ __launch_bounds__(128) void k_final(const float* __restrict__ psum, const int* __restrict__ pcount,
                                               const float* __restrict__ W_out, const float* __restrict__ b_out,
                                               float* __restrict__ out) {
    __shared__ float red[128][5];
    const int g = blockIdx.x, j = threadIdx.x;
    float cnt = fmaxf((float)pcount[g], 1.f);
    float p = psum[(long)g * HID + j] / cnt;
    #pragma unroll
    for (int o = 0; o < 5; o++) red[j][o] = p * W_out[j * 5 + o];
    __syncthreads();
    for (int off = 64; off >= 1; off >>= 1) {
        if (j < off) {
            #pragma unroll
            for (int o = 0; o < 5; o++) red[j][o] += red[j + off][o];
        }
        __syncthreads();
    }
    if (j < 5) out[g * 5 + j] = red[0][j] + b_out[j];
}

// ---------------- launch ----------------

extern "C" void kernel_launch(void* const* d_in, const int* in_sizes, int n_in,
                              void* d_out, int out_size, void* d_ws, size_t ws_size,
                              hipStream_t stream) {
    const float* x        = (const float*)d_in[0];
    const int*   eidx     = (const int*)d_in[1];
    const int*   src      = eidx;
    const int*   dst      = eidx + N_EDGES_C;
    const int*   batch    = (const int*)d_in[2];
    const float* Ws_all   = (const float*)d_in[3];
    const float* bs       = (const float*)d_in[4];
    const float* gammas   = (const float*)d_in[5];
    const float* betas    = (const float*)d_in[6];
    const float* run_mean = (const float*)d_in[7];
    const float* run_var  = (const float*)d_in[8];
    const float* W_out    = (const float*)d_in[9];
    const float* b_out    = (const float*)d_in[10];
    float* out = (float*)d_out;

    char* wp = (char*)d_ws;
    auto alloc = [&](size_t bytes) { char* p = wp; wp += (bytes + 255) & ~(size_t)255; return p; };
    float* h        = (float*)alloc((size_t)N_NODES_C * HID * 4);
    float* xw       = (float*)alloc((size_t)N_NODES_C * HID * 4);
    int*   csr_src  = (int*)alloc((size_t)N_EDGES_C * 4);
    float* csr_coef = (float*)alloc((size_t)N_EDGES_C * 4);
    int*   counts   = (int*)alloc((size_t)N_NODES_C * 4);
    int*   cursor   = (int*)alloc((size_t)N_NODES_C * 4);
    int*   offs     = (int*)alloc((size_t)(N_NODES_C + 1) * 4);
    float* norm     = (float*)alloc((size_t)N_NODES_C * 4);
    float* selfc    = (float*)alloc((size_t)N_NODES_C * 4);
    int*   tmp_incl = (int*)alloc((size_t)N_NODES_C * 4);
    int*   blockSums= (int*)alloc(512 * 4);
    int*   blockBase= (int*)alloc(512 * 4);
    float* psum     = (float*)alloc((size_t)N_GRAPHS_C * HID * 4);
    int*   pcount   = (int*)alloc((size_t)N_GRAPHS_C * 4);

    hipMemsetAsync(counts, 0, (size_t)N_NODES_C * 4, stream);
    hipMemsetAsync(cursor, 0, (size_t)N_NODES_C * 4, stream);
    hipMemsetAsync(psum,   0, (size_t)N_GRAPHS_C * HID * 4, stream);
    hipMemsetAsync(pcount, 0, (size_t)N_GRAPHS_C * 4, stream);

    const int EB = (N_EDGES_C + 255) / 256;   // 6250
    const int NB = (N_NODES_C + 255) / 256;   // 391

    k_count<<<EB, 256, 0, stream>>>(dst, counts);
    k_norm <<<NB, 256, 0, stream>>>(counts, norm, selfc);
    k_scan1<<<NB, 256, 0, stream>>>(counts, tmp_incl, blockSums);
    k_scan2<<<1, 512, 0, stream>>>(blockSums, blockBase, NB);
    k_scan3<<<NB, 256, 0, stream>>>(tmp_incl, blockBase, offs);
    k_fill <<<EB, 256, 0, stream>>>(src, dst, offs, cursor, norm, csr_src, csr_coef);

    const int GB = (N_NODES_C + 127) / 128;   // 782
    for (int l = 0; l < 4; l++) {
        const float* A = (l == 0) ? x : h;
        k_gemm<<<GB, 256, 0, stream>>>(A, Ws_all + (size_t)l * HID * HID, xw, N_NODES_C);
        k_agg<<<N_NODES_C, 128, 0, stream>>>(xw, offs, csr_src, csr_coef, selfc,
                                             bs + l * HID, run_mean + l * HID, gammas + l * HID,
                                             run_var + l * HID, betas + l * HID, h);
    }
    k_pool <<<GB, 128, 0, stream>>>(h, batch, psum, pcount);
    k_final<<<N_GRAPHS_C, 128, 0, stream>>>(psum, pcount, W_out, b_out, out);
}

// Round 2
// 886.239 us; speedup vs baseline: 1.2899x; 1.2899x over previous
//
#include <hip/hip_runtime.h>
#include <hip/hip_fp16.h>

#define N_NODES_C 100000
#define N_EDGES_C 1600000
#define N_GRAPHS_C 2000
#define HID 128
#define BN_EPS_C 1e-5f

// ---------------- CSR build ----------------

__global__ __launch_bounds__(256) void k_count(const int* __restrict__ dst, int* __restrict__ counts) {
    int e = blockIdx.x * 256 + threadIdx.x;
    if (e < N_EDGES_C) atomicAdd(&counts[dst[e]], 1);
}

__global__ __launch_bounds__(256) void k_norm(const int* __restrict__ counts, float* __restrict__ norm) {
    int i = blockIdx.x * 256 + threadIdx.x;
    if (i < N_NODES_C) norm[i] = rsqrtf((float)counts[i] + 1.0f);
}

__global__ __launch_bounds__(256) void k_scan1(const int* __restrict__ counts,
                                               int* __restrict__ tmp_incl, int* __restrict__ blockSums) {
    __shared__ int s[256];
    int i = blockIdx.x * 256 + threadIdx.x;
    int v = (i < N_NODES_C) ? counts[i] : 0;
    s[threadIdx.x] = v;
    __syncthreads();
    for (int off = 1; off < 256; off <<= 1) {
        int t = (threadIdx.x >= off) ? s[threadIdx.x - off] : 0;
        __syncthreads();
        s[threadIdx.x] += t;
        __syncthreads();
    }
    if (i < N_NODES_C) tmp_incl[i] = s[threadIdx.x];
    if (threadIdx.x == 255) blockSums[blockIdx.x] = s[255];
}

__global__ __launch_bounds__(512) void k_scan2(const int* __restrict__ blockSums,
                                               int* __restrict__ blockBase, int nblk) {
    __shared__ int s[512];
    int v = ((int)threadIdx.x < nblk) ? blockSums[threadIdx.x] : 0;
    s[threadIdx.x] = v;
    __syncthreads();
    for (int off = 1; off < 512; off <<= 1) {
        int t = (threadIdx.x >= off) ? s[threadIdx.x - off] : 0;
        __syncthreads();
        s[threadIdx.x] += t;
        __syncthreads();
    }
    if ((int)threadIdx.x < nblk) blockBase[threadIdx.x] = s[threadIdx.x] - v;  // exclusive base
}

__global__ __launch_bounds__(256) void k_scan3(const int* __restrict__ tmp_incl,
                                               const int* __restrict__ blockBase, int* __restrict__ offs) {
    int i = blockIdx.x * 256 + threadIdx.x;
    if (i < N_NODES_C) offs[i + 1] = tmp_incl[i] + blockBase[i >> 8];
    if (i == 0) offs[0] = 0;
}

__global__ __launch_bounds__(256) void k_fill(const int* __restrict__ src, const int* __restrict__ dst,
                                              const int* __restrict__ offs, int* __restrict__ cursor,
                                              int* __restrict__ csr_src) {
    int e = blockIdx.x * 256 + threadIdx.x;
    if (e < N_EDGES_C) {
        int d = dst[e];
        int p = offs[d] + atomicAdd(&cursor[d], 1);
        csr_src[p] = src[e];
    }
}

// ---------------- GEMM: Y[r,:] = norm[r] * (A[r,:] @ W), output fp16 ----------------
// Block: 256 threads -> 128 rows x 128 cols tile. Thread: 4 rows x 16 cols register tile.

__global__ __launch_bounds__(256) void k_gemm(const float* __restrict__ A, const float* __restrict__ W,
                                              const float* __restrict__ norm,
                                              __half* __restrict__ Y, int nrows) {
    __shared__ float Wl[HID * HID];
    const int tid = threadIdx.x;
    #pragma unroll
    for (int t = 0; t < 16; t++)
        ((float4*)Wl)[tid + t * 256] = ((const float4*)W)[tid + t * 256];
    __syncthreads();

    const int r0 = blockIdx.x * 128 + (tid >> 3) * 4;
    const int c0 = (tid & 7) * 16;

    float acc[4][16];
    #pragma unroll
    for (int i = 0; i < 4; i++)
        #pragma unroll
        for (int j = 0; j < 16; j++) acc[i][j] = 0.f;

    for (int k0 = 0; k0 < HID; k0 += 4) {
        float a[4][4];
        #pragma unroll
        for (int i = 0; i < 4; i++) {
            int r = r0 + i;
            float4 t = (r < nrows) ? *(const float4*)&A[(long)r * HID + k0] : make_float4(0.f, 0.f, 0.f, 0.f);
            a[i][0] = t.x; a[i][1] = t.y; a[i][2] = t.z; a[i][3] = t.w;
        }
        #pragma unroll
        for (int kk = 0; kk < 4; kk++) {
            float w[16];
            #pragma unroll
            for (int q = 0; q < 4; q++) {
                float4 t = *(const float4*)&Wl[(k0 + kk) * HID + c0 + q * 4];
                w[q * 4 + 0] = t.x; w[q * 4 + 1] = t.y; w[q * 4 + 2] = t.z; w[q * 4 + 3] = t.w;
            }
            #pragma unroll
            for (int i = 0; i < 4; i++)
                #pragma unroll
                for (int j = 0; j < 16; j++)
                    acc[i][j] = fmaf(a[i][kk], w[j], acc[i][j]);
        }
    }
    #pragma unroll
    for (int i = 0; i < 4; i++) {
        int r = r0 + i;
        if (r < nrows) {
            float s = norm[r];
            unsigned int pk[8];
            #pragma unroll
            for (int q = 0; q < 8; q++) {
                __half2 hv = __floats2half2_rn(acc[i][q * 2] * s, acc[i][q * 2 + 1] * s);
                pk[q] = *(unsigned int*)&hv;
            }
            uint4 lo = make_uint4(pk[0], pk[1], pk[2], pk[3]);
            uint4 hi = make_uint4(pk[4], pk[5], pk[6], pk[7]);
            *(uint4*)&Y[(long)r * HID + c0] = lo;
            *(uint4*)&Y[(long)r * HID + c0 + 8] = hi;
        }
    }
}

// ---------------- Aggregation + bias + BN(eval) + ReLU ----------------
// One wave (64 lanes) per node, 2 channels per lane via half2 loads.
// h_i = norm[i] * (sum_{s in N(i)} y[s] + y[i]),  y = norm .* (A@W)

__global__ __launch_bounds__(256) void k_agg(const __half* __restrict__ y, const int* __restrict__ offs,
                                             const int* __restrict__ csr_src, const float* __restrict__ norm,
                                             const float* __restrict__ bias, const float* __restrict__ mean,
                                             const float* __restrict__ gamma, const float* __restrict__ var,
                                             const float* __restrict__ beta, float* __restrict__ h) {
    const int wave = __builtin_amdgcn_readfirstlane(threadIdx.x >> 6);
    const int lane = threadIdx.x & 63;
    const int i = blockIdx.x * 4 + wave;
    const int j = lane * 2;

    const __half2* yrow = (const __half2*)&y[(long)i * HID + j];
    float2 f = __half22float2(*yrow);
    float acc0 = f.x, acc1 = f.y;

    const int e0 = offs[i], e1 = offs[i + 1];
    int e = e0;
    #define GATHER(EE) { \
        int s_ = csr_src[EE]; \
        float2 g_ = __half22float2(*(const __half2*)&y[(long)s_ * HID + j]); \
        acc0 += g_.x; acc1 += g_.y; }
    for (; e + 8 <= e1; e += 8) {
        GATHER(e) GATHER(e + 1) GATHER(e + 2) GATHER(e + 3)
        GATHER(e + 4) GATHER(e + 5) GATHER(e + 6) GATHER(e + 7)
    }
    for (; e < e1; e++) GATHER(e)
    #undef GATHER

    float ni = norm[i];
    float2 bi = *(const float2*)&bias[j];
    float2 me = *(const float2*)&mean[j];
    float2 ga = *(const float2*)&gamma[j];
    float2 va = *(const float2*)&var[j];
    float2 be = *(const float2*)&beta[j];
    float v0 = (acc0 * ni + bi.x - me.x) * (ga.x * rsqrtf(va.x + BN_EPS_C)) + be.x;
    float v1 = (acc1 * ni + bi.y - me.y) * (ga.y * rsqrtf(va.y + BN_EPS_C)) + be.y;
    *(float2*)&h[(long)i * HID + j] = make_float2(fmaxf(v0, 0.f), fmaxf(v1, 0.f));
}

// ---------------- Pooling (batch sorted -> run-length local accumulation) ----------------

__global__ __launch_bounds__(128) void k_pool(const float* __restrict__ h, const int* __restrict__ batch,
                                              float* __restrict__ psum, int* __restrict__ pcount) {
    const int j = threadIdx.x;
    const int i0 = blockIdx.x * 128;
    const int iend = min(i0 + 128, N_NODES_C);
    if (i0 >= N_NODES_C) return;
    float acc = 0.f;
    int cur = batch[i0];
    int runStart = i0;
    for (int i = i0; i < iend; i++) {
        int g = batch[i];
        if (g != cur) {
            atomicAdd(&psum[(long)cur * HID + j], acc);
            if (j == 0) atomicAdd(&pcount[cur], i - runStart);
            acc = 0.f; cur = g; runStart = i;
        }
        acc += h[(long)i * HID + j];
    }
    atomicAdd(&psum[(long)cur * HID + j], acc);
    if (j == 0) atomicAdd(&pcount[cur], iend - runStart);
}

__global__ __launch_bounds__(128) void k_final(const float* __restrict__ psum, const int* __restrict__ pcount,
                                               const float* __restrict__ W_out, const float* __restrict__ b_out,
                                               float* __restrict__ out) {
    __shared__ float red[128][5];
    const int g = blockIdx.x, j = threadIdx.x;
    float cnt = fmaxf((float)pcount[g], 1.f);
    float p = psum[(long)g * HID + j] / cnt;
    #pragma unroll
    for (int o = 0; o < 5; o++) red[j][o] = p * W_out[j * 5 + o];
    __syncthreads();
    for (int off = 64; off >= 1; off >>= 1) {
        if (j < off) {
            #pragma unroll
            for (int o = 0; o < 5; o++) red[j][o] += red[j + off][o];
        }
        __syncthreads();
    }
    if (j < 5) out[g * 5 + j] = red[0][j] + b_out[j];
}

// ---------------- launch ----------------

extern "C" void kernel_launch(void* const* d_in, const int* in_sizes, int n_in,
                              void* d_out, int out_size, void* d_ws, size_t ws_size,
                              hipStream_t stream) {
    const float* x        = (const float*)d_in[0];
    const int*   eidx     = (const int*)d_in[1];
    const int*   src      = eidx;
    const int*   dst      = eidx + N_EDGES_C;
    const int*   batch    = (const int*)d_in[2];
    const float* Ws_all   = (const float*)d_in[3];
    const float* bs       = (const float*)d_in[4];
    const float* gammas   = (const float*)d_in[5];
    const float* betas    = (const float*)d_in[6];
    const float* run_mean = (const float*)d_in[7];
    const float* run_var  = (const float*)d_in[8];
    const float* W_out    = (const float*)d_in[9];
    const float* b_out    = (const float*)d_in[10];
    float* out = (float*)d_out;

    char* wp = (char*)d_ws;
    auto alloc = [&](size_t bytes) { char* p = wp; wp += (bytes + 255) & ~(size_t)255; return p; };
    float*  h        = (float*)alloc((size_t)N_NODES_C * HID * 4);
    __half* y        = (__half*)alloc((size_t)N_NODES_C * HID * 2);
    int*    csr_src  = (int*)alloc((size_t)N_EDGES_C * 4);
    int*    counts   = (int*)alloc((size_t)N_NODES_C * 4);
    int*    cursor   = (int*)alloc((size_t)N_NODES_C * 4);
    int*    offs     = (int*)alloc((size_t)(N_NODES_C + 1) * 4);
    float*  norm     = (float*)alloc((size_t)N_NODES_C * 4);
    int*    tmp_incl = (int*)alloc((size_t)N_NODES_C * 4);
    int*    blockSums= (int*)alloc(512 * 4);
    int*    blockBase= (int*)alloc(512 * 4);
    float*  psum     = (float*)alloc((size_t)N_GRAPHS_C * HID * 4);
    int*    pcount   = (int*)alloc((size_t)N_GRAPHS_C * 4);

    hipMemsetAsync(counts, 0, (size_t)N_NODES_C * 4, stream);
    hipMemsetAsync(cursor, 0, (size_t)N_NODES_C * 4, stream);
    hipMemsetAsync(psum,   0, (size_t)N_GRAPHS_C * HID * 4, stream);
    hipMemsetAsync(pcount, 0, (size_t)N_GRAPHS_C * 4, stream);

    const int EB = (N_EDGES_C + 255) / 256;   // 6250
    const int NB = (N_NODES_C + 255) / 256;   // 391

    k_count<<<EB, 256, 0, stream>>>(dst, counts);
    k_norm <<<NB, 256, 0, stream>>>(counts, norm);
    k_scan1<<<NB, 256, 0, stream>>>(counts, tmp_incl, blockSums);
    k_scan2<<<1, 512, 0, stream>>>(blockSums, blockBase, NB);
    k_scan3<<<NB, 256, 0, stream>>>(tmp_incl, blockBase, offs);
    k_fill <<<EB, 256, 0, stream>>>(src, dst, offs, cursor, csr_src);

    const int GB = (N_NODES_C + 127) / 128;   // 782
    const int AB = (N_NODES_C + 3) / 4;       // 25000
    for (int l = 0; l < 4; l++) {
        const float* A = (l == 0) ? x : h;
        k_gemm<<<GB, 256, 0, stream>>>(A, Ws_all + (size_t)l * HID * HID, norm, y, N_NODES_C);
        k_agg<<<AB, 256, 0, stream>>>(y, offs, csr_src, norm,
                                      bs + l * HID, run_mean + l * HID, gammas + l * HID,
                                      run_var + l * HID, betas + l * HID, h);
    }
    k_pool <<<GB, 128, 0, stream>>>(h, batch, psum, pcount);
    k_final<<<N_GRAPHS_C, 128, 0, stream>>>(psum, pcount, W_out, b_out, out);
}

// Round 3
// 780.464 us; speedup vs baseline: 1.4647x; 1.1355x over previous
//
#include <hip/hip_runtime.h>
#include <hip/hip_fp16.h>

#define N_NODES_C 100000
#define N_EDGES_C 1600000
#define N_GRAPHS_C 2000
#define HID 128
#define BN_EPS_C 1e-5f
#define NBUCK 391          // ceil(100000 / 256) buckets of 256 nodes
#define PART_TILE 4096     // edges per block in hist/partition kernels

// ---------------- CSR build: bucket partition ----------------

__global__ __launch_bounds__(256) void kb_hist(const int* __restrict__ dst, int* __restrict__ bcount) {
    __shared__ int hist[NBUCK];
    const int t = threadIdx.x;
    for (int b = t; b < NBUCK; b += 256) hist[b] = 0;
    __syncthreads();
    const int e0 = blockIdx.x * PART_TILE;
    #pragma unroll
    for (int k = 0; k < 16; k++) {
        int e = e0 + k * 256 + t;
        if (e < N_EDGES_C) atomicAdd(&hist[dst[e] >> 8], 1);
    }
    __syncthreads();
    for (int b = t; b < NBUCK; b += 256) {
        int c = hist[b];
        if (c) atomicAdd(&bcount[b], c);
    }
}

__global__ __launch_bounds__(512) void kb_scan(const int* __restrict__ bcount,
                                               int* __restrict__ bbase, int* __restrict__ bcursor) {
    __shared__ int s[512];
    const int t = threadIdx.x;
    int v = (t < NBUCK) ? bcount[t] : 0;
    s[t] = v;
    __syncthreads();
    for (int off = 1; off < 512; off <<= 1) {
        int u = (t >= off) ? s[t - off] : 0;
        __syncthreads();
        s[t] += u;
        __syncthreads();
    }
    if (t < NBUCK) { int e = s[t] - v; bbase[t] = e; bcursor[t] = e; }
    if (t == 0) bbase[NBUCK] = N_EDGES_C;
}

__global__ __launch_bounds__(256) void kb_part(const int* __restrict__ src, const int* __restrict__ dst,
                                               int* __restrict__ bcursor, int2* __restrict__ ebuf) {
    __shared__ int hist[NBUCK];
    __shared__ int startA[NBUCK];
    __shared__ int lcur[NBUCK];
    const int t = threadIdx.x;
    for (int b = t; b < NBUCK; b += 256) { hist[b] = 0; lcur[b] = 0; }
    __syncthreads();
    const int e0 = blockIdx.x * PART_TILE;
    #pragma unroll
    for (int k = 0; k < 16; k++) {
        int e = e0 + k * 256 + t;
        if (e < N_EDGES_C) atomicAdd(&hist[dst[e] >> 8], 1);
    }
    __syncthreads();
    for (int b = t; b < NBUCK; b += 256) {
        int c = hist[b];
        startA[b] = c ? atomicAdd(&bcursor[b], c) : 0;
    }
    __syncthreads();
    #pragma unroll
    for (int k = 0; k < 16; k++) {
        int e = e0 + k * 256 + t;
        if (e < N_EDGES_C) {
            int d = dst[e];
            int b = d >> 8;
            int pos = startA[b] + atomicAdd(&lcur[b], 1);
            ebuf[pos] = make_int2(src[e], d);
        }
    }
}

// One block per bucket: local count+scan of 256 nodes -> offs, norm, csr_src (all writes bucket-local).
__global__ __launch_bounds__(256) void kb_fill(const int2* __restrict__ ebuf, const int* __restrict__ bbase,
                                               int* __restrict__ csr_src, int* __restrict__ offs,
                                               float* __restrict__ norm) {
    __shared__ int s[256];      // counts, then inclusive scan
    __shared__ int excl[256];
    __shared__ int lcur[256];
    const int b = blockIdx.x, t = threadIdx.x;
    const int base = b << 8;
    const int e0 = bbase[b], e1 = bbase[b + 1];
    s[t] = 0; lcur[t] = 0;
    __syncthreads();
    for (int e = e0 + t; e < e1; e += 256)
        atomicAdd(&s[ebuf[e].y & 255], 1);
    __syncthreads();
    int own = s[t];
    for (int off = 1; off < 256; off <<= 1) {
        int v = (t >= off) ? s[t - off] : 0;
        __syncthreads();
        s[t] += v;
        __syncthreads();
    }
    excl[t] = s[t] - own;
    int node = base + t;
    if (node < N_NODES_C) {
        offs[node] = e0 + (s[t] - own);
        norm[node] = rsqrtf((float)own + 1.0f);
    }
    if (b == 0 && t == 0) offs[N_NODES_C] = N_EDGES_C;
    __syncthreads();
    for (int e = e0 + t; e < e1; e += 256) {
        int2 p = ebuf[e];
        int l = p.y & 255;
        int pos = e0 + excl[l] + atomicAdd(&lcur[l], 1);
        csr_src[pos] = p.x;
    }
}

// ---------------- GEMM: Y[r,:] = norm[r] * (A[r,:] @ W), output fp16 ----------------

__global__ __launch_bounds__(256) void k_gemm(const float* __restrict__ A, const float* __restrict__ W,
                                              const float* __restrict__ norm,
                                              __half* __restrict__ Y, int nrows) {
    __shared__ float Wl[HID * HID];
    const int tid = threadIdx.x;
    #pragma unroll
    for (int t = 0; t < 16; t++)
        ((float4*)Wl)[tid + t * 256] = ((const float4*)W)[tid + t * 256];
    __syncthreads();

    const int r0 = blockIdx.x * 128 + (tid >> 3) * 4;
    const int c0 = (tid & 7) * 16;

    float acc[4][16];
    #pragma unroll
    for (int i = 0; i < 4; i++)
        #pragma unroll
        for (int j = 0; j < 16; j++) acc[i][j] = 0.f;

    for (int k0 = 0; k0 < HID; k0 += 4) {
        float a[4][4];
        #pragma unroll
        for (int i = 0; i < 4; i++) {
            int r = r0 + i;
            float4 t = (r < nrows) ? *(const float4*)&A[(long)r * HID + k0] : make_float4(0.f, 0.f, 0.f, 0.f);
            a[i][0] = t.x; a[i][1] = t.y; a[i][2] = t.z; a[i][3] = t.w;
        }
        #pragma unroll
        for (int kk = 0; kk < 4; kk++) {
            float w[16];
            #pragma unroll
            for (int q = 0; q < 4; q++) {
                float4 t = *(const float4*)&Wl[(k0 + kk) * HID + c0 + q * 4];
                w[q * 4 + 0] = t.x; w[q * 4 + 1] = t.y; w[q * 4 + 2] = t.z; w[q * 4 + 3] = t.w;
            }
            #pragma unroll
            for (int i = 0; i < 4; i++)
                #pragma unroll
                for (int j = 0; j < 16; j++)
                    acc[i][j] = fmaf(a[i][kk], w[j], acc[i][j]);
        }
    }
    #pragma unroll
    for (int i = 0; i < 4; i++) {
        int r = r0 + i;
        if (r < nrows) {
            float s = norm[r];
            unsigned int pk[8];
            #pragma unroll
            for (int q = 0; q < 8; q++) {
                __half2 hv = __floats2half2_rn(acc[i][q * 2] * s, acc[i][q * 2 + 1] * s);
                pk[q] = *(unsigned int*)&hv;
            }
            uint4 lo = make_uint4(pk[0], pk[1], pk[2], pk[3]);
            uint4 hi = make_uint4(pk[4], pk[5], pk[6], pk[7]);
            *(uint4*)&Y[(long)r * HID + c0] = lo;
            *(uint4*)&Y[(long)r * HID + c0 + 8] = hi;
        }
    }
}

// ---------------- Aggregation + bias + BN(eval) + ReLU ----------------
// One wave (64 lanes) per node, 2 channels per lane via half2 loads.
// h_i = norm[i] * (sum_{s in N(i)} y[s] + y[i]),  y = norm .* (A@W)

__global__ __launch_bounds__(256) void k_agg(const __half* __restrict__ y, const int* __restrict__ offs,
                                             const int* __restrict__ csr_src, const float* __restrict__ norm,
                                             const float* __restrict__ bias, const float* __restrict__ mean,
                                             const float* __restrict__ gamma, const float* __restrict__ var,
                                             const float* __restrict__ beta, float* __restrict__ h) {
    const int wave = __builtin_amdgcn_readfirstlane(threadIdx.x >> 6);
    const int lane = threadIdx.x & 63;
    const int i = blockIdx.x * 4 + wave;
    const int j = lane * 2;

    const __half2* yrow = (const __half2*)&y[(long)i * HID + j];
    float2 f = __half22float2(*yrow);
    float acc0 = f.x, acc1 = f.y;

    const int e0 = offs[i], e1 = offs[i + 1];
    int e = e0;
    #define GATHER(EE) { \
        int s_ = csr_src[EE]; \
        float2 g_ = __half22float2(*(const __half2*)&y[(long)s_ * HID + j]); \
        acc0 += g_.x; acc1 += g_.y; }
    for (; e + 8 <= e1; e += 8) {
        GATHER(e) GATHER(e + 1) GATHER(e + 2) GATHER(e + 3)
        GATHER(e + 4) GATHER(e + 5) GATHER(e + 6) GATHER(e + 7)
    }
    for (; e < e1; e++) GATHER(e)
    #undef GATHER

    float ni = norm[i];
    float2 bi = *(const float2*)&bias[j];
    float2 me = *(const float2*)&mean[j];
    float2 ga = *(const float2*)&gamma[j];
    float2 va = *(const float2*)&var[j];
    float2 be = *(const float2*)&beta[j];
    float v0 = (acc0 * ni + bi.x - me.x) * (ga.x * rsqrtf(va.x + BN_EPS_C)) + be.x;
    float v1 = (acc1 * ni + bi.y - me.y) * (ga.y * rsqrtf(va.y + BN_EPS_C)) + be.y;
    *(float2*)&h[(long)i * HID + j] = make_float2(fmaxf(v0, 0.f), fmaxf(v1, 0.f));
}

// ---------------- Pooling (batch sorted -> run-length local accumulation) ----------------

__global__ __launch_bounds__(128) void k_pool(const float* __restrict__ h, const int* __restrict__ batch,
                                              float* __restrict__ psum, int* __restrict__ pcount) {
    const int j = threadIdx.x;
    const int i0 = blockIdx.x * 128;
    const int iend = min(i0 + 128, N_NODES_C);
    if (i0 >= N_NODES_C) return;
    float acc = 0.f;
    int cur = batch[i0];
    int runStart = i0;
    for (int i = i0; i < iend; i++) {
        int g = batch[i];
        if (g != cur) {
            atomicAdd(&psum[(long)cur * HID + j], acc);
            if (j == 0) atomicAdd(&pcount[cur], i - runStart);
            acc = 0.f; cur = g; runStart = i;
        }
        acc += h[(long)i * HID + j];
    }
    atomicAdd(&psum[(long)cur * HID + j], acc);
    if (j == 0) atomicAdd(&pcount[cur], iend - runStart);
}

__global__ __launch_bounds__(128) void k_final(const float* __restrict__ psum, const int* __restrict__ pcount,
                                               const float* __restrict__ W_out, const float* __restrict__ b_out,
                                               float* __restrict__ out) {
    __shared__ float red[128][5];
    const int g = blockIdx.x, j = threadIdx.x;
    float cnt = fmaxf((float)pcount[g], 1.f);
    float p = psum[(long)g * HID + j] / cnt;
    #pragma unroll
    for (int o = 0; o < 5; o++) red[j][o] = p * W_out[j * 5 + o];
    __syncthreads();
    for (int off = 64; off >= 1; off >>= 1) {
        if (j < off) {
            #pragma unroll
            for (int o = 0; o < 5; o++) red[j][o] += red[j + off][o];
        }
        __syncthreads();
    }
    if (j < 5) out[g * 5 + j] = red[0][j] + b_out[j];
}

// ---------------- launch ----------------

extern "C" void kernel_launch(void* const* d_in, const int* in_sizes, int n_in,
                              void* d_out, int out_size, void* d_ws, size_t ws_size,
                              hipStream_t stream) {
    const float* x        = (const float*)d_in[0];
    const int*   eidx     = (const int*)d_in[1];
    const int*   src      = eidx;
    const int*   dst      = eidx + N_EDGES_C;
    const int*   batch    = (const int*)d_in[2];
    const float* Ws_all   = (const float*)d_in[3];
    const float* bs       = (const float*)d_in[4];
    const float* gammas   = (const float*)d_in[5];
    const float* betas    = (const float*)d_in[6];
    const float* run_mean = (const float*)d_in[7];
    const float* run_var  = (const float*)d_in[8];
    const float* W_out    = (const float*)d_in[9];
    const float* b_out    = (const float*)d_in[10];
    float* out = (float*)d_out;

    char* wp = (char*)d_ws;
    auto alloc = [&](size_t bytes) { char* p = wp; wp += (bytes + 255) & ~(size_t)255; return p; };
    float*  h        = (float*)alloc((size_t)N_NODES_C * HID * 4);
    __half* y        = (__half*)alloc((size_t)N_NODES_C * HID * 2);   // 25.6 MB
    int2*   ebuf     = (int2*)y;                                      // alias: dead before first k_gemm
    int*    csr_src  = (int*)alloc((size_t)N_EDGES_C * 4);
    int*    offs     = (int*)alloc((size_t)(N_NODES_C + 1) * 4);
    float*  norm     = (float*)alloc((size_t)N_NODES_C * 4);
    int*    bcount   = (int*)alloc((NBUCK + 1) * 4);
    int*    bbase    = (int*)alloc((NBUCK + 1) * 4);
    int*    bcursor  = (int*)alloc((NBUCK + 1) * 4);
    float*  psum     = (float*)alloc((size_t)N_GRAPHS_C * HID * 4);
    int*    pcount   = (int*)alloc((size_t)N_GRAPHS_C * 4);

    hipMemsetAsync(bcount, 0, (NBUCK + 1) * 4, stream);
    hipMemsetAsync(psum,   0, (size_t)N_GRAPHS_C * HID * 4, stream);
    hipMemsetAsync(pcount, 0, (size_t)N_GRAPHS_C * 4, stream);

    const int PB = (N_EDGES_C + PART_TILE - 1) / PART_TILE;  // 391
    kb_hist<<<PB, 256, 0, stream>>>(dst, bcount);
    kb_scan<<<1, 512, 0, stream>>>(bcount, bbase, bcursor);
    kb_part<<<PB, 256, 0, stream>>>(src, dst, bcursor, ebuf);
    kb_fill<<<NBUCK, 256, 0, stream>>>(ebuf, bbase, csr_src, offs, norm);

    const int GB = (N_NODES_C + 127) / 128;   // 782
    const int AB = (N_NODES_C + 3) / 4;       // 25000
    for (int l = 0; l < 4; l++) {
        const float* A = (l == 0) ? x : h;
        k_gemm<<<GB, 256, 0, stream>>>(A, Ws_all + (size_t)l * HID * HID, norm, y, N_NODES_C);
        k_agg<<<AB, 256, 0, stream>>>(y, offs, csr_src, norm,
                                      bs + l * HID, run_mean + l * HID, gammas + l * HID,
                                      run_var + l * HID, betas + l * HID, h);
    }
    k_pool <<<GB, 128, 0, stream>>>(h, batch, psum, pcount);
    k_final<<<N_GRAPHS_C, 128, 0, stream>>>(psum, pcount, W_out, b_out, out);
}

// Round 4
// 555.525 us; speedup vs baseline: 2.0577x; 1.4049x over previous
//
#include <hip/hip_runtime.h>
#include <hip/hip_fp16.h>

#define N_NODES_C 100000
#define N_EDGES_C 1600000
#define N_GRAPHS_C 2000
#define HID 128
#define BN_EPS_C 1e-5f
#define NBUCK 391          // ceil(100000 / 256) buckets of 256 nodes
#define PART_TILE 4096     // edges per block in hist/partition kernels

typedef _Float16 half8 __attribute__((ext_vector_type(8)));
typedef float float4v __attribute__((ext_vector_type(4)));

// ---------------- CSR build: bucket partition ----------------

__global__ __launch_bounds__(256) void kb_hist(const int* __restrict__ dst, int* __restrict__ bcount) {
    __shared__ int hist[NBUCK];
    const int t = threadIdx.x;
    for (int b = t; b < NBUCK; b += 256) hist[b] = 0;
    __syncthreads();
    const int e0 = blockIdx.x * PART_TILE;
    #pragma unroll
    for (int k = 0; k < 16; k++) {
        int e = e0 + k * 256 + t;
        if (e < N_EDGES_C) atomicAdd(&hist[dst[e] >> 8], 1);
    }
    __syncthreads();
    for (int b = t; b < NBUCK; b += 256) {
        int c = hist[b];
        if (c) atomicAdd(&bcount[b], c);
    }
}

__global__ __launch_bounds__(512) void kb_scan(const int* __restrict__ bcount,
                                               int* __restrict__ bbase, int* __restrict__ bcursor) {
    __shared__ int s[512];
    const int t = threadIdx.x;
    int v = (t < NBUCK) ? bcount[t] : 0;
    s[t] = v;
    __syncthreads();
    for (int off = 1; off < 512; off <<= 1) {
        int u = (t >= off) ? s[t - off] : 0;
        __syncthreads();
        s[t] += u;
        __syncthreads();
    }
    if (t < NBUCK) { int e = s[t] - v; bbase[t] = e; bcursor[t] = e; }
    if (t == 0) bbase[NBUCK] = N_EDGES_C;
}

__global__ __launch_bounds__(256) void kb_part(const int* __restrict__ src, const int* __restrict__ dst,
                                               int* __restrict__ bcursor, int2* __restrict__ ebuf) {
    __shared__ int hist[NBUCK];
    __shared__ int startA[NBUCK];
    __shared__ int lcur[NBUCK];
    const int t = threadIdx.x;
    for (int b = t; b < NBUCK; b += 256) { hist[b] = 0; lcur[b] = 0; }
    __syncthreads();
    const int e0 = blockIdx.x * PART_TILE;
    #pragma unroll
    for (int k = 0; k < 16; k++) {
        int e = e0 + k * 256 + t;
        if (e < N_EDGES_C) atomicAdd(&hist[dst[e] >> 8], 1);
    }
    __syncthreads();
    for (int b = t; b < NBUCK; b += 256) {
        int c = hist[b];
        startA[b] = c ? atomicAdd(&bcursor[b], c) : 0;
    }
    __syncthreads();
    #pragma unroll
    for (int k = 0; k < 16; k++) {
        int e = e0 + k * 256 + t;
        if (e < N_EDGES_C) {
            int d = dst[e];
            int b = d >> 8;
            int pos = startA[b] + atomicAdd(&lcur[b], 1);
            ebuf[pos] = make_int2(src[e], d);
        }
    }
}

// One block per bucket: local count+scan of 256 nodes -> offs, norm, csr_src (all writes bucket-local).
__global__ __launch_bounds__(256) void kb_fill(const int2* __restrict__ ebuf, const int* __restrict__ bbase,
                                               int* __restrict__ csr_src, int* __restrict__ offs,
                                               float* __restrict__ norm) {
    __shared__ int s[256];
    __shared__ int excl[256];
    __shared__ int lcur[256];
    const int b = blockIdx.x, t = threadIdx.x;
    const int base = b << 8;
    const int e0 = bbase[b], e1 = bbase[b + 1];
    s[t] = 0; lcur[t] = 0;
    __syncthreads();
    for (int e = e0 + t; e < e1; e += 256)
        atomicAdd(&s[ebuf[e].y & 255], 1);
    __syncthreads();
    int own = s[t];
    for (int off = 1; off < 256; off <<= 1) {
        int v = (t >= off) ? s[t - off] : 0;
        __syncthreads();
        s[t] += v;
        __syncthreads();
    }
    excl[t] = s[t] - own;
    int node = base + t;
    if (node < N_NODES_C) {
        offs[node] = e0 + (s[t] - own);
        norm[node] = rsqrtf((float)own + 1.0f);
    }
    if (b == 0 && t == 0) offs[N_NODES_C] = N_EDGES_C;
    __syncthreads();
    for (int e = e0 + t; e < e1; e += 256) {
        int2 p = ebuf[e];
        int l = p.y & 255;
        int pos = e0 + excl[l] + atomicAdd(&lcur[l], 1);
        csr_src[pos] = p.x;
    }
}

// ---------------- precompute: x -> fp16, W -> fp16 transposed [n][k] ----------------

__global__ __launch_bounds__(256) void k_cast(const float* __restrict__ x, _Float16* __restrict__ xh) {
    long i = ((long)blockIdx.x * 256 + threadIdx.x) * 8;
    float4 a = *(const float4*)&x[i];
    float4 b = *(const float4*)&x[i + 4];
    _Float16 p[8] = {(_Float16)a.x, (_Float16)a.y, (_Float16)a.z, (_Float16)a.w,
                     (_Float16)b.x, (_Float16)b.y, (_Float16)b.z, (_Float16)b.w};
    *(half8*)&xh[i] = *(half8*)p;
}

__global__ __launch_bounds__(256) void k_tw(const float* __restrict__ Ws_all, _Float16* __restrict__ WT) {
    int idx = blockIdx.x * 256 + threadIdx.x;     // 4*128*128 = 65536
    int l = idx >> 14, r = idx & 16383, k = r >> 7, n = r & 127;
    WT[l * 16384 + n * HID + k] = (_Float16)Ws_all[idx];
}

// ---------------- MFMA GEMM: Y[r,:] = norm[r] * (A[r,:] @ W), fp16 in/out ----------------
// Operand swap: mfma(A_op=W^T frag, B_op=node rows) -> D[channel][node]; lane holds 4
// consecutive channels for one node -> packed 8B stores. 4 waves split 128 channels.

__global__ __launch_bounds__(256) void k_gemm(const _Float16* __restrict__ Ah,
                                              const _Float16* __restrict__ WT,   // [128 n][128 k] fp16
                                              const float* __restrict__ norm,
                                              _Float16* __restrict__ Y, int nrows) {
    __shared__ _Float16 Wt[HID][136];   // [n][k], pitch 136 halves (272B: 2-way bank alias = free)
    const int tid = threadIdx.x;
    #pragma unroll
    for (int t = 0; t < 8; t++) {
        int off = tid * 8 + t * 2048;
        half8 v = *(const half8*)&WT[off];
        *(half8*)&Wt[off >> 7][off & 127] = v;
    }
    __syncthreads();

    const int wave = tid >> 6, lane = tid & 63, quad = lane >> 4, l16 = lane & 15;
    half8 Wf[2][4];
    #pragma unroll
    for (int c = 0; c < 2; c++)
        #pragma unroll
        for (int ks = 0; ks < 4; ks++)
            Wf[c][ks] = *(const half8*)&Wt[(wave * 2 + c) * 16 + l16][ks * 32 + quad * 8];

    const int nbase = blockIdx.x * 128;
    #pragma unroll
    for (int t = 0; t < 8; t++) {
        int node = nbase + t * 16 + l16;
        bool ok = node < nrows;
        half8 Af[4];
        const _Float16* arow = Ah + (long)node * HID;
        #pragma unroll
        for (int ks = 0; ks < 4; ks++)
            Af[ks] = ok ? *(const half8*)&arow[ks * 32 + quad * 8] : half8{};
        float4v a0 = {0.f, 0.f, 0.f, 0.f}, a1 = {0.f, 0.f, 0.f, 0.f};
        #pragma unroll
        for (int ks = 0; ks < 4; ks++) {
            a0 = __builtin_amdgcn_mfma_f32_16x16x32_f16(Wf[0][ks], Af[ks], a0, 0, 0, 0);
            a1 = __builtin_amdgcn_mfma_f32_16x16x32_f16(Wf[1][ks], Af[ks], a1, 0, 0, 0);
        }
        if (ok) {
            float nv = norm[node];
            _Float16 p0[4], p1[4];
            #pragma unroll
            for (int r = 0; r < 4; r++) {
                p0[r] = (_Float16)(a0[r] * nv);
                p1[r] = (_Float16)(a1[r] * nv);
            }
            *(ushort4*)&Y[(long)node * HID + (wave * 2 + 0) * 16 + quad * 4] = *(ushort4*)p0;
            *(ushort4*)&Y[(long)node * HID + (wave * 2 + 1) * 16 + quad * 4] = *(ushort4*)p1;
        }
    }
}

// ---------------- Aggregation + bias + BN(eval) + ReLU ----------------
// One wave per node, 2 channels/lane via half2. h_i = norm[i]*(sum_N y[s] + y[i]), fp16 out.

__global__ __launch_bounds__(256) void k_agg(const __half* __restrict__ y, const int* __restrict__ offs,
                                             const int* __restrict__ csr_src, const float* __restrict__ norm,
                                             const float* __restrict__ bias, const float* __restrict__ mean,
                                             const float* __restrict__ gamma, const float* __restrict__ var,
                                             const float* __restrict__ beta, __half* __restrict__ h) {
    const int wave = __builtin_amdgcn_readfirstlane(threadIdx.x >> 6);
    const int lane = threadIdx.x & 63;
    const int i = blockIdx.x * 4 + wave;
    const int j = lane * 2;

    float2 f = __half22float2(*(const __half2*)&y[(long)i * HID + j]);
    float acc0 = f.x, acc1 = f.y;

    const int e0 = offs[i], e1 = offs[i + 1];
    int e = e0;
    #define GATHER(EE) { \
        int s_ = csr_src[EE]; \
        float2 g_ = __half22float2(*(const __half2*)&y[(long)s_ * HID + j]); \
        acc0 += g_.x; acc1 += g_.y; }
    for (; e + 8 <= e1; e += 8) {
        GATHER(e) GATHER(e + 1) GATHER(e + 2) GATHER(e + 3)
        GATHER(e + 4) GATHER(e + 5) GATHER(e + 6) GATHER(e + 7)
    }
    for (; e < e1; e++) GATHER(e)
    #undef GATHER

    float ni = norm[i];
    float2 bi = *(const float2*)&bias[j];
    float2 me = *(const float2*)&mean[j];
    float2 ga = *(const float2*)&gamma[j];
    float2 va = *(const float2*)&var[j];
    float2 be = *(const float2*)&beta[j];
    float v0 = (acc0 * ni + bi.x - me.x) * (ga.x * rsqrtf(va.x + BN_EPS_C)) + be.x;
    float v1 = (acc1 * ni + bi.y - me.y) * (ga.y * rsqrtf(va.y + BN_EPS_C)) + be.y;
    *(__half2*)&h[(long)i * HID + j] = __floats2half2_rn(fmaxf(v0, 0.f), fmaxf(v1, 0.f));
}

// ---------------- Pooling (batch sorted -> run-length local accumulation) ----------------

__global__ __launch_bounds__(128) void k_pool(const __half* __restrict__ h, const int* __restrict__ batch,
                                              float* __restrict__ psum, int* __restrict__ pcount) {
    const int j = threadIdx.x;
    const int i0 = blockIdx.x * 128;
    const int iend = min(i0 + 128, N_NODES_C);
    if (i0 >= N_NODES_C) return;
    float acc = 0.f;
    int cur = batch[i0];
    int runStart = i0;
    for (int i = i0; i < iend; i++) {
        int g = batch[i];
        if (g != cur) {
            atomicAdd(&psum[(long)cur * HID + j], acc);
            if (j == 0) atomicAdd(&pcount[cur], i - runStart);
            acc = 0.f; cur = g; runStart = i;
        }
        acc += __half2float(h[(long)i * HID + j]);
    }
    atomicAdd(&psum[(long)cur * HID + j], acc);
    if (j == 0) atomicAdd(&pcount[cur], iend - runStart);
}

__global__ __launch_bounds__(128) void k_final(const float* __restrict__ psum, const int* __restrict__ pcount,
                                               const float* __restrict__ W_out, const float* __restrict__ b_out,
                                               float* __restrict__ out) {
    __shared__ float red[128][5];
    const int g = blockIdx.x, j = threadIdx.x;
    float cnt = fmaxf((float)pcount[g], 1.f);
    float p = psum[(long)g * HID + j] / cnt;
    #pragma unroll
    for (int o = 0; o < 5; o++) red[j][o] = p * W_out[j * 5 + o];
    __syncthreads();
    for (int off = 64; off >= 1; off >>= 1) {
        if (j < off) {
            #pragma unroll
            for (int o = 0; o < 5; o++) red[j][o] += red[j + off][o];
        }
        __syncthreads();
    }
    if (j < 5) out[g * 5 + j] = red[0][j] + b_out[j];
}

// ---------------- launch ----------------

extern "C" void kernel_launch(void* const* d_in, const int* in_sizes, int n_in,
                              void* d_out, int out_size, void* d_ws, size_t ws_size,
                              hipStream_t stream) {
    const float* x        = (const float*)d_in[0];
    const int*   eidx     = (const int*)d_in[1];
    const int*   src      = eidx;
    const int*   dst      = eidx + N_EDGES_C;
    const int*   batch    = (const int*)d_in[2];
    const float* Ws_all   = (const float*)d_in[3];
    const float* bs       = (const float*)d_in[4];
    const float* gammas   = (const float*)d_in[5];
    const float* betas    = (const float*)d_in[6];
    const float* run_mean = (const float*)d_in[7];
    const float* run_var  = (const float*)d_in[8];
    const float* W_out    = (const float*)d_in[9];
    const float* b_out    = (const float*)d_in[10];
    float* out = (float*)d_out;

    char* wp = (char*)d_ws;
    auto alloc = [&](size_t bytes) { char* p = wp; wp += (bytes + 255) & ~(size_t)255; return p; };
    __half*   h       = (__half*)alloc((size_t)N_NODES_C * HID * 2);
    _Float16* y       = (_Float16*)alloc((size_t)N_NODES_C * HID * 2);  // 25.6 MB
    int2*     ebuf    = (int2*)y;                                       // alias: dead before first k_gemm
    _Float16* xh      = (_Float16*)alloc((size_t)N_NODES_C * HID * 2);
    _Float16* WT      = (_Float16*)alloc((size_t)4 * HID * HID * 2);
    int*      csr_src = (int*)alloc((size_t)N_EDGES_C * 4);
    int*      offs    = (int*)alloc((size_t)(N_NODES_C + 1) * 4);
    float*    norm    = (float*)alloc((size_t)N_NODES_C * 4);
    int*      bcount  = (int*)alloc((NBUCK + 1) * 4);
    int*      bbase   = (int*)alloc((NBUCK + 1) * 4);
    int*      bcursor = (int*)alloc((NBUCK + 1) * 4);
    float*    psum    = (float*)alloc((size_t)N_GRAPHS_C * HID * 4);
    int*      pcount  = (int*)alloc((size_t)N_GRAPHS_C * 4);

    hipMemsetAsync(bcount, 0, (NBUCK + 1) * 4, stream);
    hipMemsetAsync(psum,   0, (size_t)N_GRAPHS_C * HID * 4, stream);
    hipMemsetAsync(pcount, 0, (size_t)N_GRAPHS_C * 4, stream);

    k_cast<<<(N_NODES_C * HID) / 2048, 256, 0, stream>>>(x, xh);   // 6250 blocks
    k_tw  <<<256, 256, 0, stream>>>(Ws_all, WT);

    const int PB = (N_EDGES_C + PART_TILE - 1) / PART_TILE;  // 391
    kb_hist<<<PB, 256, 0, stream>>>(dst, bcount);
    kb_scan<<<1, 512, 0, stream>>>(bcount, bbase, bcursor);
    kb_part<<<PB, 256, 0, stream>>>(src, dst, bcursor, ebuf);
    kb_fill<<<NBUCK, 256, 0, stream>>>(ebuf, bbase, csr_src, offs, norm);

    const int GB = (N_NODES_C + 127) / 128;   // 782
    const int AB = (N_NODES_C + 3) / 4;       // 25000
    for (int l = 0; l < 4; l++) {
        const _Float16* A = (l == 0) ? xh : (const _Float16*)h;
        k_gemm<<<GB, 256, 0, stream>>>(A, WT + (size_t)l * HID * HID, norm, y, N_NODES_C);
        k_agg<<<AB, 256, 0, stream>>>((const __half*)y, offs, csr_src, norm,
                                      bs + l * HID, run_mean + l * HID, gammas + l * HID,
                                      run_var + l * HID, betas + l * HID, h);
    }
    k_pool <<<GB, 128, 0, stream>>>(h, batch, psum, pcount);
    k_final<<<N_GRAPHS_C, 128, 0, stream>>>(psum, pcount, W_out, b_out, out);
}